// Round 2
// 352.232 us; speedup vs baseline: 1.0084x; 1.0084x over previous
//
#include <hip/hip_runtime.h>

// TPlanesEnc: B=4, N=131072, P=512, F=32
// coords: [B*N, 3] f32 in [-1,1]; tplanes: [3, P, P, F] f32; out: [B*N, 3*F] f32
//
// Mapping: 8 lanes per (point, plane); lane handles one float4 of the F=32
// features. Texel rows are 128B contiguous -> 8-lane float4 reads are fully
// coalesced. Output per point is 96 contiguous f32 -> coalesced float4 stores.
//
// This version:
//  - 2 independent items per thread (tid and tid+half) -> 8 texel loads in
//    flight per thread instead of 4; hides random-gather latency.
//  - nontemporal stores (clang native vector, not HIP float4 — the builtin
//    rejects HIP_vector_type) for the 201 MB output stream -> avoid evicting
//    plane data from TCC/L3 (planes are 96 MB, reused ~8x).

#define PS 512
#define FDIM 32

typedef float floatx4 __attribute__((ext_vector_type(4)));

__global__ __launch_bounds__(256) void tplanes_enc_kernel(
    const float* __restrict__ coords,   // [M, 3]
    const float* __restrict__ tplanes,  // [3, PS, PS, FDIM]
    float* __restrict__ out,            // [M, 3*FDIM]
    int M, int total, int half)
{
    int tid = blockIdx.x * blockDim.x + threadIdx.x;

    int  idxs[2];
    bool valid[2];
    idxs[0] = tid;
    idxs[1] = tid + half;
    valid[0] = idxs[0] < total;
    valid[1] = idxs[1] < total;

    const floatx4* base[2];
    int o00[2], o01[2], o10[2], o11[2];
    float fx[2], fy[2];

    // Phase 1: coords + address calc for both items (independent chains).
#pragma unroll
    for (int k = 0; k < 2; ++k) {
        if (!valid[k]) continue;
        int idx   = idxs[k];
        int chunk = idx & 7;                // FDIM/4 = 8 chunks
        int pp    = idx >> 3;               // (point, plane) pair
        int plane = pp % 3;
        int point = pp / 3;

        // [-1,1] -> [0,1]
        float cx = coords[point * 3 + 0] * 0.5f + 0.5f;
        float cy = coords[point * 3 + 1] * 0.5f + 0.5f;
        float cz = coords[point * 3 + 2] * 0.5f + 0.5f;

        // plane 0: (x,y); plane 1: (x,z); plane 2: (z,y)
        float u = (plane == 2) ? cz : cx;
        float v = (plane == 1) ? cz : cy;

        float x = fminf(fmaxf(u * (float)PS - 0.5f, 0.0f), (float)(PS - 1));
        float y = fminf(fmaxf(v * (float)PS - 0.5f, 0.0f), (float)(PS - 1));
        float x0f = floorf(x);
        float y0f = floorf(y);
        int xi0 = (int)x0f;
        int yi0 = (int)y0f;
        int xi1 = min(xi0 + 1, PS - 1);
        int yi1 = min(yi0 + 1, PS - 1);
        fx[k] = x - x0f;
        fy[k] = y - y0f;

        base[k] = (const floatx4*)(tplanes + (size_t)plane * PS * PS * FDIM);
        // float4 index of texel row (y, x): (y*PS + x)*8
        o00[k] = (yi0 * PS + xi0) * 8 + chunk;
        o01[k] = (yi0 * PS + xi1) * 8 + chunk;
        o10[k] = (yi1 * PS + xi0) * 8 + chunk;
        o11[k] = (yi1 * PS + xi1) * 8 + chunk;
    }

    // Phase 2: issue all 8 texel loads (both items) before consuming any.
    floatx4 f00[2], f01[2], f10[2], f11[2];
#pragma unroll
    for (int k = 0; k < 2; ++k) {
        if (!valid[k]) continue;
        f00[k] = base[k][o00[k]];
        f01[k] = base[k][o01[k]];
        f10[k] = base[k][o10[k]];
        f11[k] = base[k][o11[k]];
    }

    // Phase 3: bilerp + nontemporal store.
#pragma unroll
    for (int k = 0; k < 2; ++k) {
        if (!valid[k]) continue;
        float fxk = fx[k], fyk = fy[k];
        float gx = 1.0f - fxk;
        float gy = 1.0f - fyk;
        floatx4 r;
        r.x = (f00[k].x * gx + f01[k].x * fxk) * gy + (f10[k].x * gx + f11[k].x * fxk) * fyk;
        r.y = (f00[k].y * gx + f01[k].y * fxk) * gy + (f10[k].y * gx + f11[k].y * fxk) * fyk;
        r.z = (f00[k].z * gx + f01[k].z * fxk) * gy + (f10[k].z * gx + f11[k].z * fxk) * fyk;
        r.w = (f00[k].w * gx + f01[k].w * fxk) * gy + (f10[k].w * gx + f11[k].w * fxk) * fyk;
        __builtin_nontemporal_store(r, (floatx4*)out + idxs[k]);
    }
}

extern "C" void kernel_launch(void* const* d_in, const int* in_sizes, int n_in,
                              void* d_out, int out_size, void* d_ws, size_t ws_size,
                              hipStream_t stream) {
    const float* coords  = (const float*)d_in[0];
    const float* tplanes = (const float*)d_in[1];
    float* out = (float*)d_out;

    int M = in_sizes[0] / 3;            // B*N points
    int total = M * 3 * (FDIM / 4);     // one item per float4 chunk
    int half  = (total + 1) / 2;        // 2 items per thread
    int block = 256;
    int grid = (half + block - 1) / block;
    tplanes_enc_kernel<<<grid, block, 0, stream>>>(coords, tplanes, out, M, total, half);
}